// Round 1
// baseline (537.500 us; speedup 1.0000x reference)
//
#include <hip/hip_runtime.h>

// Problem constants (match reference)
#define BATCH 2048
#define NCLS  50000
#define NC4   (NCLS / 4)          // 12500, exact
#define DEG   6
#define KSCALE 30.0f
// 30 * log2(e): exp(30x) = exp2(x * KLOG2E)
#define KLOG2E 43.2808512266689f

__global__ __launch_bounds__(256) void arcface_row_kernel(
    const float* __restrict__ logits,
    const int* __restrict__ labels,
    const float* __restrict__ coeffs,
    float* __restrict__ Lout)
{
    const int row = blockIdx.x;
    const int tid = threadIdx.x;
    const float* rowp = logits + (size_t)row * NCLS;
    const float4* rp4 = (const float4*)rowp;

    // Streaming exp-sum over the row: 12500 float4 / 256 threads
    float sum = 0.0f;
    for (int j = tid; j < NC4; j += 256) {
        float4 v = rp4[j];
        sum += exp2f(v.x * KLOG2E);
        sum += exp2f(v.y * KLOG2E);
        sum += exp2f(v.z * KLOG2E);
        sum += exp2f(v.w * KLOG2E);
    }

    // wave (64-lane) reduce
    #pragma unroll
    for (int off = 32; off; off >>= 1)
        sum += __shfl_down(sum, off, 64);

    __shared__ float wsum[4];
    const int lane = tid & 63;
    const int wid  = tid >> 6;
    if (lane == 0) wsum[wid] = sum;
    __syncthreads();

    if (tid == 0) {
        float total = wsum[0] + wsum[1] + wsum[2] + wsum[3];
        const int lab = labels[row];
        // subtract this row's target column
        float others = total - exp2f(rowp[lab] * KLOG2E);

        // cos_t = logits[lab, lab]  (diagonal gather, different row!)
        float cos_t = logits[(size_t)lab * NCLS + lab];
        cos_t = fminf(fmaxf(cos_t, -1.0f + 1e-7f), 1.0f - 1e-7f);
        // (second clip to [-1,1] is a no-op)

        // Horner, descending coeffs [DEG+1]
        float a = coeffs[0];
        #pragma unroll
        for (int d = 1; d <= DEG; ++d)
            a = a * cos_t + coeffs[d];

        float num   = KSCALE * a;
        float denom = expf(num) + others;
        Lout[row]   = num - logf(denom);
    }
}

__global__ __launch_bounds__(256) void arcface_final_kernel(
    const float* __restrict__ Lvals,
    float* __restrict__ out)
{
    const int tid = threadIdx.x;
    float s = 0.0f;
    for (int i = tid; i < BATCH; i += 256)
        s += Lvals[i];

    #pragma unroll
    for (int off = 32; off; off >>= 1)
        s += __shfl_down(s, off, 64);

    __shared__ float wsum[4];
    const int lane = tid & 63;
    const int wid  = tid >> 6;
    if (lane == 0) wsum[wid] = s;
    __syncthreads();

    if (tid == 0) {
        float total = wsum[0] + wsum[1] + wsum[2] + wsum[3];
        out[0] = -(total / (float)BATCH);
    }
}

extern "C" void kernel_launch(void* const* d_in, const int* in_sizes, int n_in,
                              void* d_out, int out_size, void* d_ws, size_t ws_size,
                              hipStream_t stream)
{
    const float* logits = (const float*)d_in[0];
    const int*   labels = (const int*)d_in[1];
    const float* coeffs = (const float*)d_in[2];
    float* out  = (float*)d_out;
    float* Lbuf = (float*)d_ws;   // BATCH floats of scratch

    arcface_row_kernel<<<BATCH, 256, 0, stream>>>(logits, labels, coeffs, Lbuf);
    arcface_final_kernel<<<1, 256, 0, stream>>>(Lbuf, out);
}